// Round 2
// baseline (527.525 us; speedup 1.0000x reference)
//
#include <hip/hip_runtime.h>

typedef __bf16 bf16_t;
typedef bf16_t bf16x8 __attribute__((ext_vector_type(8)));
typedef float  f32x4  __attribute__((ext_vector_type(4)));

#define B_SZ   4
#define N_SZ   4608
#define C_SZ   64
#define KVB    32
#define QROWS  32
#define NKVT   (N_SZ / KVB)      // 144
#define NQT    (N_SZ / QROWS)    // 144
#define LDK    72                // K tile row stride (bf16 elems), 144B: balanced b128 slots
#define LDV    40                // V^T row stride, 80B
#define LDP    40                // P row stride, 80B

__device__ __forceinline__ f32x4 mfma16(bf16x8 a, bf16x8 b, f32x4 c) {
  return __builtin_amdgcn_mfma_f32_16x16x32_bf16(a, b, c, 0, 0, 0);
}

__device__ __forceinline__ float rmax16(float x) {
#pragma unroll
  for (int m = 1; m <= 8; m <<= 1) x = fmaxf(x, __shfl_xor(x, m, 64));
  return x;
}
__device__ __forceinline__ float rsum16(float x) {
#pragma unroll
  for (int m = 1; m <= 8; m <<= 1) x += __shfl_xor(x, m, 64);
  return x;
}

__global__ __launch_bounds__(64) void
attn_fwd(const float* __restrict__ q, const float* __restrict__ gamma_p,
         float* __restrict__ out) {
  __shared__ __align__(16) bf16_t khi[KVB * LDK];
  __shared__ __align__(16) bf16_t klo[KVB * LDK];
  __shared__ __align__(16) bf16_t vt [C_SZ * LDV];
  __shared__ __align__(16) bf16_t pl [QROWS * LDP];

  const int wid = blockIdx.x;          // 0..575
  const int b   = wid / NQT;
  const int qt  = wid - b * NQT;
  const int l   = threadIdx.x;         // 0..63 (one wave)
  const int c15 = l & 15;
  const int g   = l >> 4;

  const float* __restrict__ qb = q + (size_t)b * N_SZ * C_SZ;

  // ---- Q fragments (hi/lo bf16) for rows qt*32 .. +31, held in registers ----
  // A-frag (16x16x32): row = lane&15, k = (lane>>4)*8 + i
  bf16x8 qhi[2][2], qlo[2][2];   // [row-tile][k-step]
#pragma unroll
  for (int rt = 0; rt < 2; ++rt) {
#pragma unroll
    for (int ks = 0; ks < 2; ++ks) {
      const float* src = qb + (size_t)(qt*QROWS + rt*16 + c15) * C_SZ + ks*32 + g*8;
      float4 a0 = *(const float4*)(src);
      float4 a1 = *(const float4*)(src + 4);
      float vv[8] = {a0.x, a0.y, a0.z, a0.w, a1.x, a1.y, a1.z, a1.w};
#pragma unroll
      for (int i = 0; i < 8; ++i) {
        bf16_t h = (bf16_t)vv[i];
        qhi[rt][ks][i] = h;
        qlo[rt][ks][i] = (bf16_t)(vv[i] - (float)h);
      }
    }
  }

  // ---- online-softmax state + O accumulators ----
  f32x4 O[2][4];                 // [row-tile][chan-tile]
#pragma unroll
  for (int rt = 0; rt < 2; ++rt)
#pragma unroll
    for (int ct = 0; ct < 4; ++ct)
      O[rt][ct] = (f32x4){0.f, 0.f, 0.f, 0.f};
  float m_run[2][4], l_run[2][4];
#pragma unroll
  for (int rt = 0; rt < 2; ++rt)
#pragma unroll
    for (int r = 0; r < 4; ++r) { m_run[rt][r] = -3.0e38f; l_run[rt][r] = 0.f; }

  const int r2  = l >> 1;        // staging: row 0..31
  const int ch0 = (l & 1) * 32;  // staging: channel half

  for (int t = 0; t < NKVT; ++t) {
    const int kv0 = t * KVB;

    // ---- stage K tile: fp32 global -> bf16 hi/lo in LDS ----
    {
      const float* src = qb + (size_t)(kv0 + r2) * C_SZ + ch0;
#pragma unroll
      for (int jj = 0; jj < 4; ++jj) {
        float4 a0 = *(const float4*)(src + jj*8);
        float4 a1 = *(const float4*)(src + jj*8 + 4);
        float vv[8] = {a0.x, a0.y, a0.z, a0.w, a1.x, a1.y, a1.z, a1.w};
        bf16x8 h8, l8;
#pragma unroll
        for (int i = 0; i < 8; ++i) {
          bf16_t h = (bf16_t)vv[i];
          h8[i] = h;
          l8[i] = (bf16_t)(vv[i] - (float)h);
        }
        *(bf16x8*)&khi[r2*LDK + ch0 + jj*8] = h8;
        *(bf16x8*)&klo[r2*LDK + ch0 + jj*8] = l8;
      }
    }
    __syncthreads();   // staging visible (single-wave: acts as waitcnt fence)

    // ---- build V^T (bf16, = columns of khi); conflict-free column reads ----
#pragma unroll
    for (int kk = 0; kk < 4; ++kk) {
      bf16x8 col;
#pragma unroll
      for (int i = 0; i < 8; ++i) col[i] = khi[(kk*8 + i)*LDK + l];
      *(bf16x8*)&vt[l*LDV + kk*8] = col;
    }

    // ---- QK^T fragments: B-frag col = lane&15 (kv), k contiguous channels ----
    bf16x8 bh[2][2], bl[2][2];   // [kv col-tile][k-step]
#pragma unroll
    for (int ct = 0; ct < 2; ++ct)
#pragma unroll
      for (int ks = 0; ks < 2; ++ks) {
        bh[ct][ks] = *(const bf16x8*)&khi[(ct*16 + c15)*LDK + ks*32 + g*8];
        bl[ct][ks] = *(const bf16x8*)&klo[(ct*16 + c15)*LDK + ks*32 + g*8];
      }

    // ---- energy = (qhi+qlo)·(khi+klo)^T  (3-term, drop lo·lo) ----
    f32x4 s[2][2];
#pragma unroll
    for (int rt = 0; rt < 2; ++rt)
#pragma unroll
      for (int ct = 0; ct < 2; ++ct) {
        f32x4 acc = (f32x4){0.f, 0.f, 0.f, 0.f};
#pragma unroll
        for (int ks = 0; ks < 2; ++ks) {
          acc = mfma16(qhi[rt][ks], bh[ct][ks], acc);
          acc = mfma16(qhi[rt][ks], bl[ct][ks], acc);
          acc = mfma16(qlo[rt][ks], bh[ct][ks], acc);
        }
        s[rt][ct] = acc;
      }

    // ---- online softmax (rows live in 16-lane groups, reg r = row (g*4+r)) ----
#pragma unroll
    for (int rt = 0; rt < 2; ++rt) {
      float mn[4], sc[4];
#pragma unroll
      for (int r = 0; r < 4; ++r) {
        float tm = fmaxf(s[rt][0][r], s[rt][1][r]);
        tm = rmax16(tm);
        mn[r] = fmaxf(m_run[rt][r], tm);
        sc[r] = __expf(m_run[rt][r] - mn[r]);
        m_run[rt][r] = mn[r];
      }
#pragma unroll
      for (int ct = 0; ct < 2; ++ct)
#pragma unroll
        for (int r = 0; r < 4; ++r)
          s[rt][ct][r] = __expf(s[rt][ct][r] - mn[r]);
#pragma unroll
      for (int r = 0; r < 4; ++r) {
        float rs = rsum16(s[rt][0][r] + s[rt][1][r]);
        l_run[rt][r] = l_run[rt][r] * sc[r] + rs;
      }
#pragma unroll
      for (int ct = 0; ct < 4; ++ct)
#pragma unroll
        for (int r = 0; r < 4; ++r)
          O[rt][ct][r] *= sc[r];
      // write P (bf16) for A-fragment re-layout
#pragma unroll
      for (int ct = 0; ct < 2; ++ct)
#pragma unroll
        for (int r = 0; r < 4; ++r)
          pl[(rt*16 + g*4 + r)*LDP + ct*16 + c15] = (bf16_t)s[rt][ct][r];
    }
    __syncthreads();   // vt + pl visible

    // ---- PV: O += P · V  (contraction = 32 kv = one x32 step) ----
    bf16x8 vf[4];
#pragma unroll
    for (int ct = 0; ct < 4; ++ct)
      vf[ct] = *(const bf16x8*)&vt[(ct*16 + c15)*LDV + g*8];
#pragma unroll
    for (int rt = 0; rt < 2; ++rt) {
      bf16x8 pf = *(const bf16x8*)&pl[(rt*16 + c15)*LDP + g*8];
#pragma unroll
      for (int ct = 0; ct < 4; ++ct)
        O[rt][ct] = mfma16(pf, vf[ct], O[rt][ct]);
    }
    __syncthreads();   // frags consumed; safe to overwrite LDS next iter
  }

  // ---- epilogue: out = gamma * O/l + input ----
  const float gm = gamma_p[0];
#pragma unroll
  for (int rt = 0; rt < 2; ++rt)
#pragma unroll
    for (int r = 0; r < 4; ++r) {
      const float inv = 1.0f / l_run[rt][r];
      const int row = qt*QROWS + rt*16 + g*4 + r;
      const size_t base = (size_t)b * N_SZ * C_SZ + (size_t)row * C_SZ;
#pragma unroll
      for (int ct = 0; ct < 4; ++ct) {
        const int col = ct*16 + c15;
        out[base + col] = gm * (O[rt][ct][r] * inv) + qb[(size_t)row * C_SZ + col];
      }
    }
}

extern "C" void kernel_launch(void* const* d_in, const int* in_sizes, int n_in,
                              void* d_out, int out_size, void* d_ws, size_t ws_size,
                              hipStream_t stream) {
  const float* qp = (const float*)d_in[0];
  const float* gp = (const float*)d_in[1];
  float* op = (float*)d_out;
  dim3 grid(B_SZ * NQT);   // 576 one-wave blocks
  dim3 block(64);
  hipLaunchKernelGGL(attn_fwd, grid, block, 0, stream, qp, gp, op);
}

// Round 4
// 208.765 us; speedup vs baseline: 2.5269x; 2.5269x over previous
//
#include <hip/hip_runtime.h>

typedef __bf16 bf16_t;
typedef bf16_t bf16x8 __attribute__((ext_vector_type(8)));
typedef float  f32x4  __attribute__((ext_vector_type(4)));
typedef unsigned int u32;
typedef unsigned short u16;

#define B_SZ   4
#define N_SZ   4608
#define C_SZ   64
#define KVB    32
#define QROWS  32
#define NKVT   (N_SZ / KVB)     // 144
#define NQT    (N_SZ / QROWS)   // 144
#define WV     4                // waves per attn block (split-KV)
#define TPW    (NKVT / WV)      // 36 tiles per wave

__device__ __forceinline__ f32x4 mfma16(bf16x8 a, bf16x8 b, f32x4 c) {
  return __builtin_amdgcn_mfma_f32_16x16x32_bf16(a, b, c, 0, 0, 0);
}

__device__ __forceinline__ u32 pk2(float a, float b) {
  u16 ua = __builtin_bit_cast(u16, (bf16_t)a);
  u16 ub = __builtin_bit_cast(u16, (bf16_t)b);
  return (u32)ua | ((u32)ub << 16);
}

// ---- pre-kernel: fp32 input -> khi/klo (bf16 hi/lo, row-major [b][n][c])
//                             -> vt (bf16, transposed [b][c][n])
__global__ __launch_bounds__(256) void transform_k(
    const float* __restrict__ in, bf16_t* __restrict__ khi,
    bf16_t* __restrict__ klo, bf16_t* __restrict__ vt) {
  __shared__ float tile[64 * 65];
  const int bid = blockIdx.x;            // 288 blocks: (b, 64-row chunk)
  const int b  = bid / 72;
  const int n0 = (bid - b * 72) * 64;
  const int t  = threadIdx.x;
  {
    const int nl = t >> 2, c0 = (t & 3) * 16;
    const float* src = in + ((size_t)(b * N_SZ + n0 + nl)) * C_SZ + c0;
    float v[16];
    *(float4*)(v +  0) = *(const float4*)(src +  0);
    *(float4*)(v +  4) = *(const float4*)(src +  4);
    *(float4*)(v +  8) = *(const float4*)(src +  8);
    *(float4*)(v + 12) = *(const float4*)(src + 12);
    bf16x8 h8[2], l8[2];
#pragma unroll
    for (int i = 0; i < 16; ++i) {
      bf16_t h = (bf16_t)v[i];
      h8[i >> 3][i & 7] = h;
      l8[i >> 3][i & 7] = (bf16_t)(v[i] - (float)h);
      tile[nl * 65 + c0 + i] = v[i];
    }
    bf16_t* dh = khi + ((size_t)(b * N_SZ + n0 + nl)) * C_SZ + c0;
    bf16_t* dl = klo + ((size_t)(b * N_SZ + n0 + nl)) * C_SZ + c0;
    *(bf16x8*)(dh) = h8[0]; *(bf16x8*)(dh + 8) = h8[1];
    *(bf16x8*)(dl) = l8[0]; *(bf16x8*)(dl + 8) = l8[1];
  }
  __syncthreads();
  {
    const int c = t >> 2, m0 = (t & 3) * 16;
    bf16x8 o[2];
#pragma unroll
    for (int i = 0; i < 16; ++i)
      o[i >> 3][i & 7] = (bf16_t)tile[(m0 + i) * 65 + c];
    bf16_t* dst = vt + ((size_t)(b * C_SZ + c)) * N_SZ + n0 + m0;
    *(bf16x8*)(dst) = o[0]; *(bf16x8*)(dst + 8) = o[1];
  }
}

// ---- main attention: 576 blocks x 4 waves; split-KV, barrier-free hot loop
__global__ __launch_bounds__(256, 3) void attn_fwd(
    const float* __restrict__ in, const bf16_t* __restrict__ khi,
    const bf16_t* __restrict__ klo, const bf16_t* __restrict__ vt,
    const float* __restrict__ gamma_p, float* __restrict__ out) {
  __shared__ float obuf[256 * 36];            // per-wave O^T partials (pad 36 for b128-aligned, spread banks)
  __shared__ float mlbuf[4 * 2 * 2 * 16];     // [w][j][{m,l}][q16]

  const int bid0 = blockIdx.x;
  const int bid  = (bid0 & 7) * 72 + (bid0 >> 3);  // XCD swizzle (576 % 8 == 0: bijective)
  const int b  = bid / NQT;
  const int qt = bid - b * NQT;
  const int t  = threadIdx.x;
  const int w  = t >> 6, l = t & 63;
  const int c15 = l & 15, g = l >> 4;

  const bf16_t* kh_b = khi + (size_t)b * N_SZ * C_SZ;
  const bf16_t* kl_b = klo + (size_t)b * N_SZ * C_SZ;
  const bf16_t* vt_b = vt  + (size_t)b * C_SZ * N_SZ;

  // Q fragments (B-operand of swapped QK^T): B[k=ch][col=q-row]
  bf16x8 qh[2][2], ql[2][2];
#pragma unroll
  for (int j = 0; j < 2; ++j)
#pragma unroll
    for (int ks = 0; ks < 2; ++ks) {
      const size_t a = (size_t)(qt * QROWS + j * 16 + c15) * C_SZ + ks * 32 + g * 8;
      qh[j][ks] = *(const bf16x8*)(kh_b + a);
      ql[j][ks] = *(const bf16x8*)(kl_b + a);
    }

  f32x4 acc[4][2];   // O^T tiles: [c-tile][q-tile]; reg r -> c = co*16+g*4+r, q = j*16+c15
#pragma unroll
  for (int co = 0; co < 4; ++co)
#pragma unroll
    for (int j = 0; j < 2; ++j)
      acc[co][j] = (f32x4){0.f, 0.f, 0.f, 0.f};
  float m_j[2] = {-3.0e38f, -3.0e38f}, l_j[2] = {0.f, 0.f};

  const int sA = ((l >> 4) & 1) * 32 + c15;   // P-relayout source lanes
  const int sB = sA + 16;
  const bool hi_half = (l >= 32);             // selects ct = g>>1

  for (int it = 0; it < TPW; ++it) {
    const int kv0 = (w + it * WV) * KVB;      // waves interleave tiles -> L1 reuse

    // K fragments (A-operand): A[row=kv][k=ch] — direct bf16 global loads
    bf16x8 khf[2][2], klf[2][2];
#pragma unroll
    for (int ct = 0; ct < 2; ++ct)
#pragma unroll
      for (int ks = 0; ks < 2; ++ks) {
        const size_t a = (size_t)(kv0 + ct * 16 + c15) * C_SZ + ks * 32 + g * 8;
        khf[ct][ks] = *(const bf16x8*)(kh_b + a);
        klf[ct][ks] = *(const bf16x8*)(kl_b + a);
      }
    // V^T fragments (A-operand of PV): A[row=c][k=kv] — contiguous in vt
    bf16x8 vf[4];
#pragma unroll
    for (int co = 0; co < 4; ++co)
      vf[co] = *(const bf16x8*)(vt_b + (size_t)(co * 16 + c15) * N_SZ + kv0 + g * 8);

    // S^T = K·Q^T (3-term hi/lo): lane holds S[q=j*16+c15][kv=ct*16+g*4+r]
    f32x4 s[2][2];
#pragma unroll
    for (int j = 0; j < 2; ++j)
#pragma unroll
      for (int ct = 0; ct < 2; ++ct) {
        f32x4 a = (f32x4){0.f, 0.f, 0.f, 0.f};
#pragma unroll
        for (int ks = 0; ks < 2; ++ks) {
          a = mfma16(khf[ct][ks], qh[j][ks], a);
          a = mfma16(khf[ct][ks], ql[j][ks], a);
          a = mfma16(klf[ct][ks], qh[j][ks], a);
        }
        s[j][ct] = a;
      }

#pragma unroll
    for (int j = 0; j < 2; ++j) {
      // row max: 8 in-lane + 2 shuffles (kv axis = regs + 4 lane-groups)
      float mx = fmaxf(fmaxf(fmaxf(s[j][0][0], s[j][0][1]), fmaxf(s[j][0][2], s[j][0][3])),
                       fmaxf(fmaxf(s[j][1][0], s[j][1][1]), fmaxf(s[j][1][2], s[j][1][3])));
      mx = fmaxf(mx, __shfl_xor(mx, 16, 64));
      mx = fmaxf(mx, __shfl_xor(mx, 32, 64));
      const float mn = fmaxf(m_j[j], mx);
      const float sc = __expf(m_j[j] - mn);
      m_j[j] = mn;
      float rs = 0.f;
#pragma unroll
      for (int ct = 0; ct < 2; ++ct)
#pragma unroll
        for (int r = 0; r < 4; ++r) {
          const float e = __expf(s[j][ct][r] - mn);
          s[j][ct][r] = e;
          rs += e;
        }
      rs += __shfl_xor(rs, 16, 64);
      rs += __shfl_xor(rs, 32, 64);
      l_j[j] = l_j[j] * sc + rs;
#pragma unroll
      for (int co = 0; co < 4; ++co)
        acc[co][j] *= sc;

      // P (bf16 pairs) -> B-fragment of PV via 8 bpermutes + 4 selects
      const u32 L0 = pk2(s[j][0][0], s[j][0][1]);
      const u32 H0 = pk2(s[j][0][2], s[j][0][3]);
      const u32 L1 = pk2(s[j][1][0], s[j][1][1]);
      const u32 H1 = pk2(s[j][1][2], s[j][1][3]);
      const u32 aL0 = (u32)__shfl((int)L0, sA, 64);
      const u32 aL1 = (u32)__shfl((int)L1, sA, 64);
      const u32 aH0 = (u32)__shfl((int)H0, sA, 64);
      const u32 aH1 = (u32)__shfl((int)H1, sA, 64);
      const u32 bL0 = (u32)__shfl((int)L0, sB, 64);
      const u32 bL1 = (u32)__shfl((int)L1, sB, 64);
      const u32 bH0 = (u32)__shfl((int)H0, sB, 64);
      const u32 bH1 = (u32)__shfl((int)H1, sB, 64);
      union { u32 u[4]; bf16x8 v; } pf;
      pf.u[0] = hi_half ? aL1 : aL0;
      pf.u[1] = hi_half ? aH1 : aH0;
      pf.u[2] = hi_half ? bL1 : bL0;
      pf.u[3] = hi_half ? bH1 : bH0;
#pragma unroll
      for (int co = 0; co < 4; ++co)
        acc[co][j] = mfma16(vf[co], pf.v, acc[co][j]);
    }
  }

  // ---- flash-combine the 4 waves' partials in LDS ----
  float* ob = obuf + (size_t)(w * 64 + l) * 36;
#pragma unroll
  for (int co = 0; co < 4; ++co)
#pragma unroll
    for (int j = 0; j < 2; ++j)
      *(f32x4*)(ob + (co * 2 + j) * 4) = acc[co][j];
  if (g == 0) {
#pragma unroll
    for (int j = 0; j < 2; ++j) {
      mlbuf[((w * 2 + j) * 2 + 0) * 16 + c15] = m_j[j];
      mlbuf[((w * 2 + j) * 2 + 1) * 16 + c15] = l_j[j];
    }
  }
  __syncthreads();

  // wave w merges + writes channel tile co = w
  const float gm = gamma_p[0];
#pragma unroll
  for (int j = 0; j < 2; ++j) {
    float mw[4];
#pragma unroll
    for (int wp = 0; wp < 4; ++wp)
      mw[wp] = mlbuf[((wp * 2 + j) * 2 + 0) * 16 + c15];
    const float ms = fmaxf(fmaxf(mw[0], mw[1]), fmaxf(mw[2], mw[3]));
    float ls = 0.f;
    f32x4 mg = (f32x4){0.f, 0.f, 0.f, 0.f};
#pragma unroll
    for (int wp = 0; wp < 4; ++wp) {
      const float cf = __expf(mw[wp] - ms);
      ls += cf * mlbuf[((wp * 2 + j) * 2 + 1) * 16 + c15];
      const f32x4 pv = *(const f32x4*)(obuf + (size_t)(wp * 64 + l) * 36 + (w * 2 + j) * 4);
      mg += pv * cf;
    }
    const float inv = 1.0f / ls;
    const int q  = qt * QROWS + j * 16 + c15;
    const int cb = w * 16 + g * 4;
    const size_t base = ((size_t)(b * N_SZ + q)) * C_SZ + cb;
    const float4 iv = *(const float4*)(in + base);
    float4 ov;
    ov.x = gm * (mg[0] * inv) + iv.x;
    ov.y = gm * (mg[1] * inv) + iv.y;
    ov.z = gm * (mg[2] * inv) + iv.z;
    ov.w = gm * (mg[3] * inv) + iv.w;
    *(float4*)(out + base) = ov;
  }
}

extern "C" void kernel_launch(void* const* d_in, const int* in_sizes, int n_in,
                              void* d_out, int out_size, void* d_ws, size_t ws_size,
                              hipStream_t stream) {
  const float* in = (const float*)d_in[0];
  const float* gp = (const float*)d_in[1];
  float* op = (float*)d_out;
  const size_t plane = (size_t)B_SZ * N_SZ * C_SZ;   // 1.18M bf16 elems
  bf16_t* khi = (bf16_t*)d_ws;
  bf16_t* klo = khi + plane;
  bf16_t* vt  = klo + plane;                          // total 7.08 MB of ws
  hipLaunchKernelGGL(transform_k, dim3(288), dim3(256), 0, stream, in, khi, klo, vt);
  hipLaunchKernelGGL(attn_fwd, dim3(B_SZ * NQT), dim3(256), 0, stream,
                     in, khi, klo, vt, gp, op);
}